// Round 4
// baseline (505.173 us; speedup 1.0000x reference)
//
#include <hip/hip_runtime.h>
#include <hip/hip_bf16.h>
#include <stdint.h>

typedef __bf16 bf16_t;
typedef bf16_t bf16x8 __attribute__((ext_vector_type(8)));
typedef float f32x4 __attribute__((ext_vector_type(4)));

#define D_IN 64
#define D_OUT 64
#define NTHREADS 256   // 4 waves/block, each wave independent

// ---------------- pre-pass 1: feats fp32 -> bf16 (+ zero row at index N) ----
__global__ void convert_feats(const float* __restrict__ feats,
                              bf16_t* __restrict__ fb,
                              int n_elems, int total8) {
    int g = blockIdx.x * blockDim.x + threadIdx.x;
    for (; g < total8; g += gridDim.x * blockDim.x) {
        const int e = g * 8;
        bf16x8 v = {};
        if (e < n_elems) {
            f32x4 a = *(const f32x4*)(feats + e);
            f32x4 b = *(const f32x4*)(feats + e + 4);
            #pragma unroll
            for (int i = 0; i < 4; ++i) {
                v[i]     = (bf16_t)a[i];
                v[i + 4] = (bf16_t)b[i];
            }
        }
        *(bf16x8*)(fb + e) = v;
    }
}

// ---------------- pre-pass 2: weight -> transposed bf16: wt[k][dp][d] -------
__global__ void convert_weight(const float* __restrict__ w,
                               bf16_t* __restrict__ wt, int k3) {
    const int k = blockIdx.x;
    const int tid = threadIdx.x;              // 512
    const int dp = tid >> 3;
    const int d0 = (tid & 7) * 8;
    const float* src = w + (size_t)k * (D_IN * D_OUT) + (size_t)d0 * D_OUT + dp;
    bf16x8 v;
    #pragma unroll
    for (int j = 0; j < 8; ++j) v[j] = (bf16_t)src[j * D_OUT];
    *(bf16x8*)((char*)wt + (size_t)k * 8192 + dp * 128 + d0 * 2) = v;
}

// ---------------- main kernel: register-direct, LDS-free, barrier-free ------
__global__ void subm_conv_rd(
    const bf16_t* __restrict__ fb,      // (N+1) rows x 128 B, row N = zeros
    const int* __restrict__ idxT,       // [k3][n_vox]
    const bf16_t* __restrict__ wt,      // [k3][64][64] bf16, wt[k][dp][d]
    float* __restrict__ out,
    int n_vox, int k3)
{
    const int lane = threadIdx.x & 63;
    const int wv   = threadIdx.x >> 6;
    const int l15  = lane & 15;
    const int l4   = lane >> 4;
    const int wrow = (blockIdx.x * (NTHREADS / 64) + wv) * 32;  // wave's 32 rows
    const int r0   = wrow + l15;        // gather row for m=0 group
    const int r1   = wrow + 16 + l15;   // gather row for m=1 group

    f32x4 acc[2][4];
    #pragma unroll
    for (int m = 0; m < 2; ++m)
        #pragma unroll
        for (int n = 0; n < 4; ++n)
            acc[m][n] = (f32x4){0.f, 0.f, 0.f, 0.f};

    #define LDIDX(kk, j0, j1) do {                                             \
        const int* ip_ = idxT + (size_t)(kk) * n_vox;                          \
        j0 = (r0 < n_vox) ? ip_[r0] : -1;                                      \
        j1 = (r1 < n_vox) ? ip_[r1] : -1;                                      \
    } while (0)

    #define AROWP(j) ((const char*)fb + \
        (size_t)(((j) >= 0 && (j) < n_vox) ? (j) : n_vox) * 128)

    // idx pipeline 2-deep; A-fragment prefetch 1-deep
    int ic0, ic1, in0, in1;
    LDIDX(0, ic0, ic1);
    if (k3 > 1) { LDIDX(1, in0, in1); } else { in0 = ic0; in1 = ic1; }

    bf16x8 a00, a01, a10, a11;          // a[m][ks] for current k
    {
        const char* p0 = AROWP(ic0);
        const char* p1 = AROWP(ic1);
        a00 = *(const bf16x8*)(p0 +      l4 * 16);
        a01 = *(const bf16x8*)(p0 + 64 + l4 * 16);
        a10 = *(const bf16x8*)(p1 +      l4 * 16);
        a11 = *(const bf16x8*)(p1 + 64 + l4 * 16);
    }

    for (int k = 0; k < k3; ++k) {
        // idx for k+2
        int t0, t1;
        if (k + 2 < k3) { LDIDX(k + 2, t0, t1); } else { t0 = in0; t1 = in1; }

        // A prefetch for k+1 (gather latency hides under this iter's MFMA)
        bf16x8 na00, na01, na10, na11;
        {
            const char* p0 = AROWP(in0);
            const char* p1 = AROWP(in1);
            na00 = *(const bf16x8*)(p0 +      l4 * 16);
            na01 = *(const bf16x8*)(p0 + 64 + l4 * 16);
            na10 = *(const bf16x8*)(p1 +      l4 * 16);
            na11 = *(const bf16x8*)(p1 + 64 + l4 * 16);
        }

        // B fragments for k (L1/L2-hot, fully coalesced 64B-line pattern)
        const char* wb = (const char*)wt + (size_t)k * 8192 + l15 * 128 + l4 * 16;
        bf16x8 b00 = *(const bf16x8*)(wb + 0 * 2048);
        bf16x8 b01 = *(const bf16x8*)(wb + 0 * 2048 + 64);
        bf16x8 b10 = *(const bf16x8*)(wb + 1 * 2048);
        bf16x8 b11 = *(const bf16x8*)(wb + 1 * 2048 + 64);
        bf16x8 b20 = *(const bf16x8*)(wb + 2 * 2048);
        bf16x8 b21 = *(const bf16x8*)(wb + 2 * 2048 + 64);
        bf16x8 b30 = *(const bf16x8*)(wb + 3 * 2048);
        bf16x8 b31 = *(const bf16x8*)(wb + 3 * 2048 + 64);

        // 16 MFMA: 2 K-chunks x 2 row-groups x 4 col-groups
        acc[0][0] = __builtin_amdgcn_mfma_f32_16x16x32_bf16(a00, b00, acc[0][0], 0, 0, 0);
        acc[0][1] = __builtin_amdgcn_mfma_f32_16x16x32_bf16(a00, b10, acc[0][1], 0, 0, 0);
        acc[0][2] = __builtin_amdgcn_mfma_f32_16x16x32_bf16(a00, b20, acc[0][2], 0, 0, 0);
        acc[0][3] = __builtin_amdgcn_mfma_f32_16x16x32_bf16(a00, b30, acc[0][3], 0, 0, 0);
        acc[1][0] = __builtin_amdgcn_mfma_f32_16x16x32_bf16(a10, b00, acc[1][0], 0, 0, 0);
        acc[1][1] = __builtin_amdgcn_mfma_f32_16x16x32_bf16(a10, b10, acc[1][1], 0, 0, 0);
        acc[1][2] = __builtin_amdgcn_mfma_f32_16x16x32_bf16(a10, b20, acc[1][2], 0, 0, 0);
        acc[1][3] = __builtin_amdgcn_mfma_f32_16x16x32_bf16(a10, b30, acc[1][3], 0, 0, 0);
        acc[0][0] = __builtin_amdgcn_mfma_f32_16x16x32_bf16(a01, b01, acc[0][0], 0, 0, 0);
        acc[0][1] = __builtin_amdgcn_mfma_f32_16x16x32_bf16(a01, b11, acc[0][1], 0, 0, 0);
        acc[0][2] = __builtin_amdgcn_mfma_f32_16x16x32_bf16(a01, b21, acc[0][2], 0, 0, 0);
        acc[0][3] = __builtin_amdgcn_mfma_f32_16x16x32_bf16(a01, b31, acc[0][3], 0, 0, 0);
        acc[1][0] = __builtin_amdgcn_mfma_f32_16x16x32_bf16(a11, b01, acc[1][0], 0, 0, 0);
        acc[1][1] = __builtin_amdgcn_mfma_f32_16x16x32_bf16(a11, b11, acc[1][1], 0, 0, 0);
        acc[1][2] = __builtin_amdgcn_mfma_f32_16x16x32_bf16(a11, b21, acc[1][2], 0, 0, 0);
        acc[1][3] = __builtin_amdgcn_mfma_f32_16x16x32_bf16(a11, b31, acc[1][3], 0, 0, 0);

        // rotate pipelines
        a00 = na00; a01 = na01; a10 = na10; a11 = na11;
        ic0 = in0; ic1 = in1; in0 = t0; in1 = t1;
    }

    // C/D layout: col = lane&15, row = (lane>>4)*4 + reg
    #pragma unroll
    for (int m = 0; m < 2; ++m)
        #pragma unroll
        for (int n = 0; n < 4; ++n)
            #pragma unroll
            for (int j = 0; j < 4; ++j) {
                const int row = wrow + m * 16 + l4 * 4 + j;
                const int col = n * 16 + l15;
                if (row < n_vox)
                    out[(size_t)row * D_OUT + col] = acc[m][n][j];
            }
    #undef LDIDX
    #undef AROWP
}

// ---------------- fallback (round-1 kernel, used if ws too small) ----------
typedef float f32x4_ __attribute__((ext_vector_type(4)));
__global__ __launch_bounds__(512, 1) void subm_conv_mfma_v1(
    const float* __restrict__ feats,
    const int* __restrict__ indices,
    const float* __restrict__ weight,
    float* __restrict__ out,
    int n_vox, int k3)
{
    __shared__ bf16_t As[128 * 64];
    __shared__ bf16_t Bs[64 * 64];

    const int tid  = threadIdx.x;
    const int lane = tid & 63;
    const int wv   = tid >> 6;
    const int wr   = (wv >> 1) * 32;
    const int wc   = (wv & 1) * 32;
    const int l15  = lane & 15;
    const int l4   = lane >> 4;
    const int n0   = blockIdx.x * 128;

    const int ar = tid >> 2;
    const int ac = (tid & 3) * 16;
    const int bdp = tid & 63;
    const int bd0 = (tid >> 6) * 8;

    auto swz = [](int row, int col) -> uint32_t {
        return (uint32_t)((row * 128 + col * 2) ^ ((row & 7) << 4));
    };

    f32x4 acc[2][2];
    #pragma unroll
    for (int i = 0; i < 2; ++i)
        #pragma unroll
        for (int j = 0; j < 2; ++j)
            acc[i][j] = (f32x4){0.f, 0.f, 0.f, 0.f};

    for (int k = 0; k < k3; ++k) {
        __syncthreads();
        {
            const int n = n0 + ar;
            int idx = (n < n_vox) ? indices[(size_t)k * n_vox + n] : -1;
            bf16x8 v0 = {}, v1 = {};
            if (idx >= 0) {
                const float* src = feats + (size_t)idx * D_IN + ac;
                f32x4 f0 = *(const f32x4*)(src + 0);
                f32x4 f1 = *(const f32x4*)(src + 4);
                f32x4 f2 = *(const f32x4*)(src + 8);
                f32x4 f3 = *(const f32x4*)(src + 12);
                #pragma unroll
                for (int i = 0; i < 4; ++i) {
                    v0[i]     = (bf16_t)f0[i];
                    v0[i + 4] = (bf16_t)f1[i];
                    v1[i]     = (bf16_t)f2[i];
                    v1[i + 4] = (bf16_t)f3[i];
                }
            }
            *(bf16x8*)((char*)As + swz(ar, ac))     = v0;
            *(bf16x8*)((char*)As + swz(ar, ac + 8)) = v1;
        }
        {
            const float* wsrc = weight + (size_t)k * (D_IN * D_OUT) + (size_t)bd0 * D_OUT + bdp;
            bf16x8 v;
            #pragma unroll
            for (int i = 0; i < 8; ++i) v[i] = (bf16_t)wsrc[i * D_OUT];
            *(bf16x8*)((char*)Bs + swz(bdp, bd0)) = v;
        }
        __syncthreads();
        #pragma unroll
        for (int ks = 0; ks < 2; ++ks) {
            const int kc = ks * 32 + l4 * 8;
            bf16x8 a0 = *(const bf16x8*)((char*)As + swz(wr + l15,      kc));
            bf16x8 a1 = *(const bf16x8*)((char*)As + swz(wr + 16 + l15, kc));
            bf16x8 b0 = *(const bf16x8*)((char*)Bs + swz(wc + l15,      kc));
            bf16x8 b1 = *(const bf16x8*)((char*)Bs + swz(wc + 16 + l15, kc));
            acc[0][0] = __builtin_amdgcn_mfma_f32_16x16x32_bf16(a0, b0, acc[0][0], 0, 0, 0);
            acc[0][1] = __builtin_amdgcn_mfma_f32_16x16x32_bf16(a0, b1, acc[0][1], 0, 0, 0);
            acc[1][0] = __builtin_amdgcn_mfma_f32_16x16x32_bf16(a1, b0, acc[1][0], 0, 0, 0);
            acc[1][1] = __builtin_amdgcn_mfma_f32_16x16x32_bf16(a1, b1, acc[1][1], 0, 0, 0);
        }
    }

    #pragma unroll
    for (int mi = 0; mi < 2; ++mi)
        #pragma unroll
        for (int ni = 0; ni < 2; ++ni)
            #pragma unroll
            for (int j = 0; j < 4; ++j) {
                const int row = n0 + wr + mi * 16 + l4 * 4 + j;
                const int col = wc + ni * 16 + l15;
                if (row < n_vox)
                    out[(size_t)row * D_OUT + col] = acc[mi][ni][j];
            }
}

extern "C" void kernel_launch(void* const* d_in, const int* in_sizes, int n_in,
                              void* d_out, int out_size, void* d_ws, size_t ws_size,
                              hipStream_t stream) {
    const float* feats   = (const float*)d_in[0];
    const int*   indices = (const int*)d_in[1];
    const float* weight  = (const float*)d_in[2];
    float* out = (float*)d_out;

    const int n_vox = in_sizes[0] / D_IN;
    const int k3    = in_sizes[2] / (D_IN * D_OUT);

    const size_t fb_bytes  = (size_t)(n_vox + 1) * D_IN * sizeof(bf16_t);
    const size_t wt_off    = (fb_bytes + 255) & ~(size_t)255;
    const size_t wt_bytes  = (size_t)k3 * 64 * 64 * sizeof(bf16_t);
    const size_t need      = wt_off + wt_bytes;

    if (ws_size >= need && k3 >= 1) {
        bf16_t* fb = (bf16_t*)((char*)d_ws);
        bf16_t* wt = (bf16_t*)((char*)d_ws + wt_off);

        const int n_elems = n_vox * D_IN;
        const int total8  = (n_vox + 1) * (D_IN / 8);
        int cblocks = (total8 + 255) / 256;
        if (cblocks > 2048) cblocks = 2048;
        convert_feats<<<cblocks, 256, 0, stream>>>(feats, fb, n_elems, total8);
        convert_weight<<<k3, 512, 0, stream>>>(weight, wt, k3);

        const int waves = (n_vox + 31) / 32;
        const int grid  = (waves + (NTHREADS / 64) - 1) / (NTHREADS / 64);
        subm_conv_rd<<<grid, NTHREADS, 0, stream>>>(fb, indices, wt, out, n_vox, k3);
    } else {
        const int grid = (n_vox + 127) / 128;
        subm_conv_mfma_v1<<<grid, 512, 0, stream>>>(feats, indices, weight, out, n_vox, k3);
    }
}

// Round 5
// 407.698 us; speedup vs baseline: 1.2391x; 1.2391x over previous
//
#include <hip/hip_runtime.h>
#include <hip/hip_bf16.h>
#include <stdint.h>

typedef __bf16 bf16_t;
typedef bf16_t bf16x8 __attribute__((ext_vector_type(8)));
typedef float f32x4 __attribute__((ext_vector_type(4)));

#define D_IN 64
#define D_OUT 64
#define NTHREADS 256      // 4 waves/block, waves fully independent (no barriers)

#define GLOAD_LDS16(gsrc, ldst)                                                     \
    __builtin_amdgcn_global_load_lds(                                               \
        (const __attribute__((address_space(1))) uint32_t*)(gsrc),                  \
        (__attribute__((address_space(3))) uint32_t*)(ldst), 16, 0, 0)

// ---------------- pre-pass 1: feats fp32 -> bf16 (+ zero row at index N) ----
__global__ void convert_feats(const float* __restrict__ feats,
                              bf16_t* __restrict__ fb,
                              int n_elems, int total8) {
    int g = blockIdx.x * blockDim.x + threadIdx.x;
    for (; g < total8; g += gridDim.x * blockDim.x) {
        const int e = g * 8;
        bf16x8 v = {};
        if (e < n_elems) {
            f32x4 a = *(const f32x4*)(feats + e);
            f32x4 b = *(const f32x4*)(feats + e + 4);
            #pragma unroll
            for (int i = 0; i < 4; ++i) {
                v[i]     = (bf16_t)a[i];
                v[i + 4] = (bf16_t)b[i];
            }
        }
        *(bf16x8*)(fb + e) = v;
    }
}

// ---------------- pre-pass 2: weight -> transposed bf16: wt[k][dp][d] -------
__global__ void convert_weight(const float* __restrict__ w,
                               bf16_t* __restrict__ wt, int k3) {
    const int k = blockIdx.x;
    const int tid = threadIdx.x;              // 512
    const int dp = tid >> 3;
    const int d0 = (tid & 7) * 8;
    const float* src = w + (size_t)k * (D_IN * D_OUT) + (size_t)d0 * D_OUT + dp;
    bf16x8 v;
    #pragma unroll
    for (int j = 0; j < 8; ++j) v[j] = (bf16_t)src[j * D_OUT];
    *(bf16x8*)((char*)wt + (size_t)k * 8192 + dp * 128 + d0 * 2) = v;
}

// ---------------- main kernel: wave-private LDS, barrier-free, depth-2 ------
// Per wave: 32 output rows x 64 cols, acc[2][4]. A staged into a private
// 3 x 4KB LDS ring via global_load_lds (pre-swizzled source chunks); stage
// depth 2; manual counted vmcnt(16) (one body = 16 VMEM ops); B loaded
// register-direct each iter BEFORE idx/stage so its wait never drains stage.
__global__ __launch_bounds__(NTHREADS, 3) void subm_conv_wp(
    const bf16_t* __restrict__ fb,      // (N+1) rows x 128 B, row N = zeros
    const int* __restrict__ idxT,       // [k3][n_vox]
    const bf16_t* __restrict__ wt,      // [k3][64][64] bf16, wt[k][dp][d]
    float* __restrict__ out,
    int n_vox, int k3)
{
    __shared__ __align__(16) char lds[4 * 3 * 4096];   // 48 KB: 4 waves x 3 bufs

    const int lane = threadIdx.x & 63;
    const int wv   = threadIdx.x >> 6;
    const int l15  = lane & 15;
    const int l4   = lane >> 4;
    const int wrow = (blockIdx.x * (NTHREADS / 64) + wv) * 32;
    char* const ldsb = lds + wv * 12288;

    // staging geometry: gload_lds #s covers rows s*8 + (lane>>3), slot lane&7
    const int rb = wrow + (lane >> 3);              // base gather row
    const uint32_t so = (uint32_t)(((lane & 7) ^ ((lane >> 3) & 7)) * 16);
    const uint32_t xr = (uint32_t)(l15 & 7);        // read-side XOR (row&7)

    f32x4 acc[2][4];
    #pragma unroll
    for (int m = 0; m < 2; ++m)
        #pragma unroll
        for (int n = 0; n < 4; ++n)
            acc[m][n] = (f32x4){0.f, 0.f, 0.f, 0.f};

    #define IDX4(kk, d0_, d1_, d2_, d3_) do {                                  \
        const int* ip_ = idxT + (size_t)(kk) * n_vox + rb;                     \
        d0_ = (rb      < n_vox) ? ip_[0]  : -1;                                \
        d1_ = (rb + 8  < n_vox) ? ip_[8]  : -1;                                \
        d2_ = (rb + 16 < n_vox) ? ip_[16] : -1;                                \
        d3_ = (rb + 24 < n_vox) ? ip_[24] : -1;                                \
    } while (0)

    #define STAGE4(lb_, u0_, u1_, u2_, u3_) do {                               \
        GLOAD_LDS16((const char*)fb + (size_t)((u0_) < 0 ? n_vox : (u0_)) * 128 + so, (lb_));          \
        GLOAD_LDS16((const char*)fb + (size_t)((u1_) < 0 ? n_vox : (u1_)) * 128 + so, (lb_) + 1024);   \
        GLOAD_LDS16((const char*)fb + (size_t)((u2_) < 0 ? n_vox : (u2_)) * 128 + so, (lb_) + 2048);   \
        GLOAD_LDS16((const char*)fb + (size_t)((u3_) < 0 ? n_vox : (u3_)) * 128 + so, (lb_) + 3072);   \
    } while (0)

    // One pipeline body. Issue order (fence-bounded by the asm waitcnt):
    //   [vmcnt(WN)] ds_read A(k) ; B(k) x8 ; idx(k+3) x4 ; stage(k+2) x4 ; MFMA
    #define BODY(WN, kk, iu0, iu1, iu2, iu3, id0, id1, id2, id3) do {          \
        asm volatile("s_waitcnt vmcnt(" WN ")" ::: "memory");                  \
        const char* ab_ = ldsb + bc * 4096;                                    \
        bf16x8 a00 = *(const bf16x8*)(ab_ + l15 * 128        + (((uint32_t)l4       ^ xr) * 16)); \
        bf16x8 a01 = *(const bf16x8*)(ab_ + l15 * 128        + (((uint32_t)(4 + l4) ^ xr) * 16)); \
        bf16x8 a10 = *(const bf16x8*)(ab_ + (16 + l15) * 128 + (((uint32_t)l4       ^ xr) * 16)); \
        bf16x8 a11 = *(const bf16x8*)(ab_ + (16 + l15) * 128 + (((uint32_t)(4 + l4) ^ xr) * 16)); \
        const char* wb_ = (const char*)wt + (size_t)(kk) * 8192 + l15 * 128 + l4 * 16;            \
        bf16x8 b00 = *(const bf16x8*)(wb_ + 0 * 2048);                         \
        bf16x8 b01 = *(const bf16x8*)(wb_ + 0 * 2048 + 64);                    \
        bf16x8 b10 = *(const bf16x8*)(wb_ + 1 * 2048);                         \
        bf16x8 b11 = *(const bf16x8*)(wb_ + 1 * 2048 + 64);                    \
        bf16x8 b20 = *(const bf16x8*)(wb_ + 2 * 2048);                         \
        bf16x8 b21 = *(const bf16x8*)(wb_ + 2 * 2048 + 64);                    \
        bf16x8 b30 = *(const bf16x8*)(wb_ + 3 * 2048);                         \
        bf16x8 b31 = *(const bf16x8*)(wb_ + 3 * 2048 + 64);                    \
        { const int kI_ = ((kk) + 3 < k3) ? (kk) + 3 : k3 - 1;                 \
          IDX4(kI_, id0, id1, id2, id3); }                                     \
        STAGE4(ldsb + bs * 4096, iu0, iu1, iu2, iu3);                          \
        acc[0][0] = __builtin_amdgcn_mfma_f32_16x16x32_bf16(a00, b00, acc[0][0], 0, 0, 0); \
        acc[0][1] = __builtin_amdgcn_mfma_f32_16x16x32_bf16(a00, b10, acc[0][1], 0, 0, 0); \
        acc[0][2] = __builtin_amdgcn_mfma_f32_16x16x32_bf16(a00, b20, acc[0][2], 0, 0, 0); \
        acc[0][3] = __builtin_amdgcn_mfma_f32_16x16x32_bf16(a00, b30, acc[0][3], 0, 0, 0); \
        acc[1][0] = __builtin_amdgcn_mfma_f32_16x16x32_bf16(a10, b00, acc[1][0], 0, 0, 0); \
        acc[1][1] = __builtin_amdgcn_mfma_f32_16x16x32_bf16(a10, b10, acc[1][1], 0, 0, 0); \
        acc[1][2] = __builtin_amdgcn_mfma_f32_16x16x32_bf16(a10, b20, acc[1][2], 0, 0, 0); \
        acc[1][3] = __builtin_amdgcn_mfma_f32_16x16x32_bf16(a10, b30, acc[1][3], 0, 0, 0); \
        acc[0][0] = __builtin_amdgcn_mfma_f32_16x16x32_bf16(a01, b01, acc[0][0], 0, 0, 0); \
        acc[0][1] = __builtin_amdgcn_mfma_f32_16x16x32_bf16(a01, b11, acc[0][1], 0, 0, 0); \
        acc[0][2] = __builtin_amdgcn_mfma_f32_16x16x32_bf16(a01, b21, acc[0][2], 0, 0, 0); \
        acc[0][3] = __builtin_amdgcn_mfma_f32_16x16x32_bf16(a01, b31, acc[0][3], 0, 0, 0); \
        acc[1][0] = __builtin_amdgcn_mfma_f32_16x16x32_bf16(a11, b01, acc[1][0], 0, 0, 0); \
        acc[1][1] = __builtin_amdgcn_mfma_f32_16x16x32_bf16(a11, b11, acc[1][1], 0, 0, 0); \
        acc[1][2] = __builtin_amdgcn_mfma_f32_16x16x32_bf16(a11, b21, acc[1][2], 0, 0, 0); \
        acc[1][3] = __builtin_amdgcn_mfma_f32_16x16x32_bf16(a11, b31, acc[1][3], 0, 0, 0); \
        bc = (bc == 2) ? 0 : bc + 1;                                           \
        bs = (bs == 2) ? 0 : bs + 1;                                           \
    } while (0)

    // ---- prologue: idx(0),(1) transient; idx(2)->A; stage(0), stage(1) ----
    int iA0, iA1, iA2, iA3, iB0, iB1, iB2, iB3;
    {
        int j0, j1, j2, j3, m0, m1, m2, m3;
        IDX4(0, j0, j1, j2, j3);
        IDX4(1, m0, m1, m2, m3);
        IDX4(2, iA0, iA1, iA2, iA3);
        STAGE4(ldsb, j0, j1, j2, j3);
        STAGE4(ldsb + 4096, m0, m1, m2, m3);
    }

    int bc = 0, bs = 2;
    // peeled body 0: prologue order isn't fence-bounded -> conservative drain
    BODY("0", 0, iA0, iA1, iA2, iA3, iB0, iB1, iB2, iB3);
    int k = 1;
    for (; k + 1 < k3; k += 2) {
        BODY("16", k,     iB0, iB1, iB2, iB3, iA0, iA1, iA2, iA3);
        BODY("16", k + 1, iA0, iA1, iA2, iA3, iB0, iB1, iB2, iB3);
    }
    if (k < k3) {   // even k3 tail
        BODY("16", k, iB0, iB1, iB2, iB3, iA0, iA1, iA2, iA3);
    }

    // C/D layout: col = lane&15, row = (lane>>4)*4 + reg
    #pragma unroll
    for (int m = 0; m < 2; ++m)
        #pragma unroll
        for (int n = 0; n < 4; ++n)
            #pragma unroll
            for (int j = 0; j < 4; ++j) {
                const int row = wrow + m * 16 + l4 * 4 + j;
                const int col = n * 16 + l15;
                if (row < n_vox)
                    out[(size_t)row * D_OUT + col] = acc[m][n][j];
            }
    #undef BODY
    #undef STAGE4
    #undef IDX4
}

// ---------------- fallback (round-1 kernel) --------------------------------
__global__ __launch_bounds__(512, 1) void subm_conv_mfma_v1(
    const float* __restrict__ feats,
    const int* __restrict__ indices,
    const float* __restrict__ weight,
    float* __restrict__ out,
    int n_vox, int k3)
{
    __shared__ bf16_t As[128 * 64];
    __shared__ bf16_t Bs[64 * 64];

    const int tid  = threadIdx.x;
    const int lane = tid & 63;
    const int wv   = tid >> 6;
    const int wr   = (wv >> 1) * 32;
    const int wc   = (wv & 1) * 32;
    const int l15  = lane & 15;
    const int l4   = lane >> 4;
    const int n0   = blockIdx.x * 128;

    const int ar = tid >> 2;
    const int ac = (tid & 3) * 16;
    const int bdp = tid & 63;
    const int bd0 = (tid >> 6) * 8;

    auto swz = [](int row, int col) -> uint32_t {
        return (uint32_t)((row * 128 + col * 2) ^ ((row & 7) << 4));
    };

    f32x4 acc[2][2];
    #pragma unroll
    for (int i = 0; i < 2; ++i)
        #pragma unroll
        for (int j = 0; j < 2; ++j)
            acc[i][j] = (f32x4){0.f, 0.f, 0.f, 0.f};

    for (int k = 0; k < k3; ++k) {
        __syncthreads();
        {
            const int n = n0 + ar;
            int idx = (n < n_vox) ? indices[(size_t)k * n_vox + n] : -1;
            bf16x8 v0 = {}, v1 = {};
            if (idx >= 0) {
                const float* src = feats + (size_t)idx * D_IN + ac;
                f32x4 f0 = *(const f32x4*)(src + 0);
                f32x4 f1 = *(const f32x4*)(src + 4);
                f32x4 f2 = *(const f32x4*)(src + 8);
                f32x4 f3 = *(const f32x4*)(src + 12);
                #pragma unroll
                for (int i = 0; i < 4; ++i) {
                    v0[i]     = (bf16_t)f0[i];
                    v0[i + 4] = (bf16_t)f1[i];
                    v1[i]     = (bf16_t)f2[i];
                    v1[i + 4] = (bf16_t)f3[i];
                }
            }
            *(bf16x8*)((char*)As + swz(ar, ac))     = v0;
            *(bf16x8*)((char*)As + swz(ar, ac + 8)) = v1;
        }
        {
            const float* wsrc = weight + (size_t)k * (D_IN * D_OUT) + (size_t)bd0 * D_OUT + bdp;
            bf16x8 v;
            #pragma unroll
            for (int i = 0; i < 8; ++i) v[i] = (bf16_t)wsrc[i * D_OUT];
            *(bf16x8*)((char*)Bs + swz(bdp, bd0)) = v;
        }
        __syncthreads();
        #pragma unroll
        for (int ks = 0; ks < 2; ++ks) {
            const int kc = ks * 32 + l4 * 8;
            bf16x8 a0 = *(const bf16x8*)((char*)As + swz(wr + l15,      kc));
            bf16x8 a1 = *(const bf16x8*)((char*)As + swz(wr + 16 + l15, kc));
            bf16x8 b0 = *(const bf16x8*)((char*)Bs + swz(wc + l15,      kc));
            bf16x8 b1 = *(const bf16x8*)((char*)Bs + swz(wc + 16 + l15, kc));
            acc[0][0] = __builtin_amdgcn_mfma_f32_16x16x32_bf16(a0, b0, acc[0][0], 0, 0, 0);
            acc[0][1] = __builtin_amdgcn_mfma_f32_16x16x32_bf16(a0, b1, acc[0][1], 0, 0, 0);
            acc[1][0] = __builtin_amdgcn_mfma_f32_16x16x32_bf16(a1, b0, acc[1][0], 0, 0, 0);
            acc[1][1] = __builtin_amdgcn_mfma_f32_16x16x32_bf16(a1, b1, acc[1][1], 0, 0, 0);
        }
    }

    #pragma unroll
    for (int mi = 0; mi < 2; ++mi)
        #pragma unroll
        for (int ni = 0; ni < 2; ++ni)
            #pragma unroll
            for (int j = 0; j < 4; ++j) {
                const int row = n0 + wr + mi * 16 + l4 * 4 + j;
                const int col = wc + ni * 16 + l15;
                if (row < n_vox)
                    out[(size_t)row * D_OUT + col] = acc[mi][ni][j];
            }
}

extern "C" void kernel_launch(void* const* d_in, const int* in_sizes, int n_in,
                              void* d_out, int out_size, void* d_ws, size_t ws_size,
                              hipStream_t stream) {
    const float* feats   = (const float*)d_in[0];
    const int*   indices = (const int*)d_in[1];
    const float* weight  = (const float*)d_in[2];
    float* out = (float*)d_out;

    const int n_vox = in_sizes[0] / D_IN;
    const int k3    = in_sizes[2] / (D_IN * D_OUT);

    const size_t fb_bytes  = (size_t)(n_vox + 1) * D_IN * sizeof(bf16_t);
    const size_t wt_off    = (fb_bytes + 255) & ~(size_t)255;
    const size_t wt_bytes  = (size_t)k3 * 64 * 64 * sizeof(bf16_t);
    const size_t need      = wt_off + wt_bytes;

    if (ws_size >= need && k3 >= 4) {
        bf16_t* fb = (bf16_t*)((char*)d_ws);
        bf16_t* wt = (bf16_t*)((char*)d_ws + wt_off);

        const int n_elems = n_vox * D_IN;
        const int total8  = (n_vox + 1) * (D_IN / 8);
        int cblocks = (total8 + 255) / 256;
        if (cblocks > 2048) cblocks = 2048;
        convert_feats<<<cblocks, 256, 0, stream>>>(feats, fb, n_elems, total8);
        convert_weight<<<k3, 512, 0, stream>>>(weight, wt, k3);

        const int grid = (n_vox + 127) / 128;   // 128 rows per 4-wave block
        subm_conv_wp<<<grid, NTHREADS, 0, stream>>>(fb, indices, wt, out, n_vox, k3);
    } else {
        const int grid = (n_vox + 127) / 128;
        subm_conv_mfma_v1<<<grid, 512, 0, stream>>>(feats, indices, weight, out, n_vox, k3);
    }
}

// Round 6
// 400.476 us; speedup vs baseline: 1.2614x; 1.0180x over previous
//
#include <hip/hip_runtime.h>
#include <hip/hip_bf16.h>
#include <stdint.h>

typedef __bf16 bf16_t;
typedef bf16_t bf16x8 __attribute__((ext_vector_type(8)));
typedef float f32x4 __attribute__((ext_vector_type(4)));

#define D_IN 64
#define D_OUT 64
#define BM 128
#define NTHREADS 512

#define GLOAD_LDS16(gsrc, ldst)                                                     \
    __builtin_amdgcn_global_load_lds(                                               \
        (const __attribute__((address_space(1))) uint32_t*)(gsrc),                  \
        (__attribute__((address_space(3))) uint32_t*)(ldst), 16, 0, 0)

// XOR-swizzled byte offset into a [rows][64] bf16 tile (row stride 128 B).
__device__ __forceinline__ uint32_t swz(int row, int col) {
    return (uint32_t)((row * 128 + col * 2) ^ ((row & 7) << 4));
}

// ---------------- pre-pass 1: feats fp32 -> bf16 (+ zero row at index N) ----
__global__ void convert_feats(const float* __restrict__ feats,
                              bf16_t* __restrict__ fb,
                              int n_elems, int total8) {
    int g = blockIdx.x * blockDim.x + threadIdx.x;
    for (; g < total8; g += gridDim.x * blockDim.x) {
        const int e = g * 8;
        bf16x8 v = {};
        if (e < n_elems) {
            f32x4 a = *(const f32x4*)(feats + e);
            f32x4 b = *(const f32x4*)(feats + e + 4);
            #pragma unroll
            for (int i = 0; i < 4; ++i) {
                v[i]     = (bf16_t)a[i];
                v[i + 4] = (bf16_t)b[i];
            }
        }
        *(bf16x8*)(fb + e) = v;
    }
}

// ---------------- pre-pass 2: weight -> plain transposed bf16 wt[k][dp][d] --
__global__ void convert_weight(const float* __restrict__ w,
                               bf16_t* __restrict__ wt, int k3) {
    const int k = blockIdx.x;
    const int tid = threadIdx.x;              // 512
    const int dp = tid >> 3;
    const int d0 = (tid & 7) * 8;
    const float* src = w + (size_t)k * (D_IN * D_OUT) + (size_t)d0 * D_OUT + dp;
    bf16x8 v;
    #pragma unroll
    for (int j = 0; j < 8; ++j) v[j] = (bf16_t)src[j * D_OUT];
    *(bf16x8*)((char*)wt + (size_t)k * 8192 + dp * 128 + d0 * 2) = v;
}

// ---------------- main kernel: R2 structure, A-only LDS, register B ---------
// 4 blocks/CU (32 KB LDS, <=64 VGPR target) -> 32 waves/CU theoretical.
__global__ __launch_bounds__(NTHREADS, 8) void subm_conv_hi(
    const bf16_t* __restrict__ fb,      // (N+1) rows x 128 B, row N = zeros
    const int* __restrict__ indices,
    const bf16_t* __restrict__ wt,      // [k3][64][64] bf16, wt[k][dp][d]
    float* __restrict__ out,
    int n_vox, int k3)
{
    __shared__ __align__(16) bf16_t As[2][BM * 64];   // 2 x 16 KB only

    const int tid  = threadIdx.x;
    const int lane = tid & 63;
    const int wv   = tid >> 6;
    const int l15  = lane & 15;
    const int l4   = lane >> 4;
    const int wr   = (wv >> 1) * 32;
    const int wc   = (wv & 1) * 32;
    const int n0   = blockIdx.x * BM;

    // A-staging: wave wv stages tile rows [wv*16, wv*16+16), 2 issues of 8 rows
    const int rA0 = wv * 16 + (lane >> 3);
    const int rA1 = rA0 + 8;
    const int cp  = lane & 7;
    const uint32_t so0 = (uint32_t)((cp ^ (rA0 & 7)) * 16);  // pre-swizzled src
    const uint32_t so1 = (uint32_t)((cp ^ (rA1 & 7)) * 16);

    int ia0 = -1, ia1 = -1;

    #define LOADIDX(kk) do {                                                   \
        const int* ip = indices + (size_t)(kk) * n_vox + n0;                   \
        ia0 = (n0 + rA0 < n_vox) ? ip[rA0] : -1;                               \
        ia1 = (n0 + rA1 < n_vox) ? ip[rA1] : -1;                               \
    } while (0)

    #define STAGE(buf, kk) do {                                                \
        const size_t r0_ = (size_t)((ia0 >= 0 && ia0 < n_vox) ? ia0 : n_vox);  \
        const size_t r1_ = (size_t)((ia1 >= 0 && ia1 < n_vox) ? ia1 : n_vox);  \
        GLOAD_LDS16((const char*)fb + r0_ * 128 + so0,                         \
                    (char*)&As[buf][0] + wv * 2048);                           \
        GLOAD_LDS16((const char*)fb + r1_ * 128 + so1,                         \
                    (char*)&As[buf][0] + wv * 2048 + 1024);                    \
    } while (0)

    f32x4 acc[2][2];
    #pragma unroll
    for (int i = 0; i < 2; ++i)
        #pragma unroll
        for (int j = 0; j < 2; ++j)
            acc[i][j] = (f32x4){0.f, 0.f, 0.f, 0.f};

    LOADIDX(0);
    STAGE(0, 0);
    if (k3 > 1) LOADIDX(1);

    for (int k = 0; k < k3; ++k) {
        // drains vmcnt(0): stage(k) complete
        __syncthreads();

        // B fragments for k (global, L1/L2-hot; wave's 32 cols x 64 d).
        // MUST be issued before the stage ops: vmcnt is in-order, so waiting
        // on B must not imply waiting on stage(k+1).
        const char* wb = (const char*)wt + (size_t)k * 8192
                       + (size_t)(wc + l15) * 128 + l4 * 16;
        bf16x8 b00 = *(const bf16x8*)(wb);              // g0, ks0
        bf16x8 b01 = *(const bf16x8*)(wb + 64);         // g0, ks1
        bf16x8 b10 = *(const bf16x8*)(wb + 2048);       // g1 (+16 dp), ks0
        bf16x8 b11 = *(const bf16x8*)(wb + 2048 + 64);  // g1, ks1
        __builtin_amdgcn_sched_barrier(0);   // keep B loads above the stage

        if (k + 1 < k3) STAGE((k + 1) & 1, k + 1);   // in flight across MFMA
        if (k + 2 < k3) LOADIDX(k + 2);

        const char* ab = (const char*)&As[k & 1][0];
        {   // ks = 0
            const int kc = l4 * 8;
            bf16x8 a0 = *(const bf16x8*)(ab + swz(wr + l15,      kc));
            bf16x8 a1 = *(const bf16x8*)(ab + swz(wr + 16 + l15, kc));
            acc[0][0] = __builtin_amdgcn_mfma_f32_16x16x32_bf16(a0, b00, acc[0][0], 0, 0, 0);
            acc[0][1] = __builtin_amdgcn_mfma_f32_16x16x32_bf16(a0, b10, acc[0][1], 0, 0, 0);
            acc[1][0] = __builtin_amdgcn_mfma_f32_16x16x32_bf16(a1, b00, acc[1][0], 0, 0, 0);
            acc[1][1] = __builtin_amdgcn_mfma_f32_16x16x32_bf16(a1, b10, acc[1][1], 0, 0, 0);
        }
        {   // ks = 1
            const int kc = 32 + l4 * 8;
            bf16x8 a0 = *(const bf16x8*)(ab + swz(wr + l15,      kc));
            bf16x8 a1 = *(const bf16x8*)(ab + swz(wr + 16 + l15, kc));
            acc[0][0] = __builtin_amdgcn_mfma_f32_16x16x32_bf16(a0, b01, acc[0][0], 0, 0, 0);
            acc[0][1] = __builtin_amdgcn_mfma_f32_16x16x32_bf16(a0, b11, acc[0][1], 0, 0, 0);
            acc[1][0] = __builtin_amdgcn_mfma_f32_16x16x32_bf16(a1, b01, acc[1][0], 0, 0, 0);
            acc[1][1] = __builtin_amdgcn_mfma_f32_16x16x32_bf16(a1, b11, acc[1][1], 0, 0, 0);
        }
    }

    // C/D layout: col = lane&15, row = (lane>>4)*4 + reg
    #pragma unroll
    for (int mi = 0; mi < 2; ++mi)
        #pragma unroll
        for (int ni = 0; ni < 2; ++ni)
            #pragma unroll
            for (int j = 0; j < 4; ++j) {
                const int row = n0 + wr + mi * 16 + l4 * 4 + j;
                const int col = wc + ni * 16 + l15;
                if (row < n_vox)
                    out[(size_t)row * D_OUT + col] = acc[mi][ni][j];
            }
    #undef LOADIDX
    #undef STAGE
}

// ---------------- fallback (round-1 kernel) --------------------------------
__global__ __launch_bounds__(512, 1) void subm_conv_mfma_v1(
    const float* __restrict__ feats,
    const int* __restrict__ indices,
    const float* __restrict__ weight,
    float* __restrict__ out,
    int n_vox, int k3)
{
    __shared__ bf16_t As[128 * 64];
    __shared__ bf16_t Bs[64 * 64];

    const int tid  = threadIdx.x;
    const int lane = tid & 63;
    const int wv   = tid >> 6;
    const int wr   = (wv >> 1) * 32;
    const int wc   = (wv & 1) * 32;
    const int l15  = lane & 15;
    const int l4   = lane >> 4;
    const int n0   = blockIdx.x * 128;

    const int ar = tid >> 2;
    const int ac = (tid & 3) * 16;
    const int bdp = tid & 63;
    const int bd0 = (tid >> 6) * 8;

    f32x4 acc[2][2];
    #pragma unroll
    for (int i = 0; i < 2; ++i)
        #pragma unroll
        for (int j = 0; j < 2; ++j)
            acc[i][j] = (f32x4){0.f, 0.f, 0.f, 0.f};

    for (int k = 0; k < k3; ++k) {
        __syncthreads();
        {
            const int n = n0 + ar;
            int idx = (n < n_vox) ? indices[(size_t)k * n_vox + n] : -1;
            bf16x8 v0 = {}, v1 = {};
            if (idx >= 0) {
                const float* src = feats + (size_t)idx * D_IN + ac;
                f32x4 f0 = *(const f32x4*)(src + 0);
                f32x4 f1 = *(const f32x4*)(src + 4);
                f32x4 f2 = *(const f32x4*)(src + 8);
                f32x4 f3 = *(const f32x4*)(src + 12);
                #pragma unroll
                for (int i = 0; i < 4; ++i) {
                    v0[i]     = (bf16_t)f0[i];
                    v0[i + 4] = (bf16_t)f1[i];
                    v1[i]     = (bf16_t)f2[i];
                    v1[i + 4] = (bf16_t)f3[i];
                }
            }
            *(bf16x8*)((char*)As + swz(ar, ac))     = v0;
            *(bf16x8*)((char*)As + swz(ar, ac + 8)) = v1;
        }
        {
            const float* wsrc = weight + (size_t)k * (D_IN * D_OUT) + (size_t)bd0 * D_OUT + bdp;
            bf16x8 v;
            #pragma unroll
            for (int i = 0; i < 8; ++i) v[i] = (bf16_t)wsrc[i * D_OUT];
            *(bf16x8*)((char*)Bs + swz(bdp, bd0)) = v;
        }
        __syncthreads();
        #pragma unroll
        for (int ks = 0; ks < 2; ++ks) {
            const int kc = ks * 32 + l4 * 8;
            bf16x8 a0 = *(const bf16x8*)((char*)As + swz(wr + l15,      kc));
            bf16x8 a1 = *(const bf16x8*)((char*)As + swz(wr + 16 + l15, kc));
            bf16x8 b0 = *(const bf16x8*)((char*)Bs + swz(wc + l15,      kc));
            bf16x8 b1 = *(const bf16x8*)((char*)Bs + swz(wc + 16 + l15, kc));
            acc[0][0] = __builtin_amdgcn_mfma_f32_16x16x32_bf16(a0, b0, acc[0][0], 0, 0, 0);
            acc[0][1] = __builtin_amdgcn_mfma_f32_16x16x32_bf16(a0, b1, acc[0][1], 0, 0, 0);
            acc[1][0] = __builtin_amdgcn_mfma_f32_16x16x32_bf16(a1, b0, acc[1][0], 0, 0, 0);
            acc[1][1] = __builtin_amdgcn_mfma_f32_16x16x32_bf16(a1, b1, acc[1][1], 0, 0, 0);
        }
    }

    #pragma unroll
    for (int mi = 0; mi < 2; ++mi)
        #pragma unroll
        for (int ni = 0; ni < 2; ++ni)
            #pragma unroll
            for (int j = 0; j < 4; ++j) {
                const int row = n0 + wr + mi * 16 + l4 * 4 + j;
                const int col = wc + ni * 16 + l15;
                if (row < n_vox)
                    out[(size_t)row * D_OUT + col] = acc[mi][ni][j];
            }
}

extern "C" void kernel_launch(void* const* d_in, const int* in_sizes, int n_in,
                              void* d_out, int out_size, void* d_ws, size_t ws_size,
                              hipStream_t stream) {
    const float* feats   = (const float*)d_in[0];
    const int*   indices = (const int*)d_in[1];
    const float* weight  = (const float*)d_in[2];
    float* out = (float*)d_out;

    const int n_vox = in_sizes[0] / D_IN;
    const int k3    = in_sizes[2] / (D_IN * D_OUT);
    const int grid  = (n_vox + BM - 1) / BM;

    const size_t fb_bytes  = (size_t)(n_vox + 1) * D_IN * sizeof(bf16_t);
    const size_t wt_off    = (fb_bytes + 255) & ~(size_t)255;
    const size_t wt_bytes  = (size_t)k3 * 64 * 64 * sizeof(bf16_t);
    const size_t need      = wt_off + wt_bytes;

    if (ws_size >= need && k3 >= 2) {
        bf16_t* fb = (bf16_t*)((char*)d_ws);
        bf16_t* wt = (bf16_t*)((char*)d_ws + wt_off);

        const int n_elems = n_vox * D_IN;
        const int total8  = (n_vox + 1) * (D_IN / 8);
        int cblocks = (total8 + 255) / 256;
        if (cblocks > 2048) cblocks = 2048;
        convert_feats<<<cblocks, 256, 0, stream>>>(feats, fb, n_elems, total8);
        convert_weight<<<k3, 512, 0, stream>>>(weight, wt, k3);
        subm_conv_hi<<<grid, NTHREADS, 0, stream>>>(fb, indices, wt, out, n_vox, k3);
    } else {
        subm_conv_mfma_v1<<<grid, 512, 0, stream>>>(feats, indices, weight, out, n_vox, k3);
    }
}

// Round 7
// 257.544 us; speedup vs baseline: 1.9615x; 1.5550x over previous
//
#include <hip/hip_runtime.h>
#include <hip/hip_bf16.h>
#include <stdint.h>

typedef __bf16 bf16_t;
typedef bf16_t bf16x8 __attribute__((ext_vector_type(8)));
typedef float f32x4 __attribute__((ext_vector_type(4)));

#define D_IN 64
#define D_OUT 64
#define BM 256
#define NTHREADS 512

#define GLOAD_LDS16(gsrc, ldst)                                                     \
    __builtin_amdgcn_global_load_lds(                                               \
        (const __attribute__((address_space(1))) uint32_t*)(gsrc),                  \
        (__attribute__((address_space(3))) uint32_t*)(ldst), 16, 0, 0)

// XOR-swizzled byte offset into a [rows][64] bf16 tile (row stride 128 B).
__device__ __forceinline__ uint32_t swz(int row, int col) {
    return (uint32_t)((row * 128 + col * 2) ^ ((row & 7) << 4));
}

// ---------------- pre-pass 1: feats fp32 -> bf16 (+ zero row at index N) ----
__global__ void convert_feats(const float* __restrict__ feats,
                              bf16_t* __restrict__ fb,
                              int n_elems, int total8) {
    int g = blockIdx.x * blockDim.x + threadIdx.x;
    for (; g < total8; g += gridDim.x * blockDim.x) {
        const int e = g * 8;
        bf16x8 v = {};
        if (e < n_elems) {
            f32x4 a = *(const f32x4*)(feats + e);
            f32x4 b = *(const f32x4*)(feats + e + 4);
            #pragma unroll
            for (int i = 0; i < 4; ++i) {
                v[i]     = (bf16_t)a[i];
                v[i + 4] = (bf16_t)b[i];
            }
        }
        *(bf16x8*)(fb + e) = v;
    }
}

// ---------------- pre-pass 2: weight -> transposed + inverse-swizzled bf16 --
// wtb[k] is the 8 KB LDS image as written linearly by global_load_lds: slot
// (dp = t>>3, c' = t&7) holds logical chunk c = c' ^ (dp&7) of Wt[dp][*],
// where Wt[dp][d] = W[k][d][dp].
__global__ void convert_weight(const float* __restrict__ w,
                               bf16_t* __restrict__ wtb, int k3) {
    const int k = blockIdx.x;
    const int tid = threadIdx.x;              // 512
    const int dp = tid >> 3;
    const int cp = tid & 7;
    const int d0 = (cp ^ (dp & 7)) * 8;
    const float* src = w + (size_t)k * (D_IN * D_OUT) + (size_t)d0 * D_OUT + dp;
    bf16x8 v;
    #pragma unroll
    for (int j = 0; j < 8; ++j) v[j] = (bf16_t)src[j * D_OUT];
    *(bf16x8*)((char*)wtb + (size_t)k * 8192 + tid * 16) = v;
}

// ---------------- main kernel: R2 structure, BM=256 (2x work per barrier) ---
// 8 waves as 4(row) x 2(col); each wave: 64 rows x 32 cols = acc[4][2].
// Stage depth 1 (identical to R2); the doubled MFMA phase covers gather
// latency, and the per-iter barrier-drain stall amortizes over 2x bytes.
__global__ __launch_bounds__(NTHREADS, 4) void subm_conv_256(
    const bf16_t* __restrict__ fb,      // (N+1) rows x 128 B, row N = zeros
    const int* __restrict__ indices,
    const bf16_t* __restrict__ wtb,     // k3 x 8192 B, pre-swizzled
    float* __restrict__ out,
    int n_vox, int k3)
{
    __shared__ __align__(16) bf16_t As[2][BM * 64];   // 2 x 32 KB
    __shared__ __align__(16) bf16_t Bs[2][64 * 64];   // 2 x  8 KB  (80 KB)

    const int tid  = threadIdx.x;
    const int lane = tid & 63;
    const int wv   = tid >> 6;
    const int l15  = lane & 15;
    const int l4   = lane >> 4;
    const int wr   = (wv >> 1) * 64;    // wave row base: 0,64,128,192
    const int wc   = (wv & 1) * 32;     // wave col base: 0,32
    const int n0   = blockIdx.x * BM;

    // A-staging: wave wv stages rows [wv*32, wv*32+32) = 4 issues of 8 rows.
    // Per issue s: rows wv*32 + s*8 + (lane>>3), chunk lane&7 (XOR pre-swizzled
    // on the global source so the LDS image matches swz()).
    const int rbase = wv * 32 + (lane >> 3);
    const uint32_t so = (uint32_t)(((lane & 7) ^ ((lane >> 3) & 7)) * 16);

    int ia0, ia1, ia2, ia3;   // gathered idx for the NEXT tile to stage

    #define LOADIDX(kk) do {                                                   \
        const int* ip = indices + (size_t)(kk) * n_vox + n0 + rbase;           \
        ia0 = (n0 + rbase      < n_vox) ? ip[0]  : -1;                         \
        ia1 = (n0 + rbase + 8  < n_vox) ? ip[8]  : -1;                         \
        ia2 = (n0 + rbase + 16 < n_vox) ? ip[16] : -1;                         \
        ia3 = (n0 + rbase + 24 < n_vox) ? ip[24] : -1;                         \
    } while (0)

    #define STAGE(buf, kk) do {                                                \
        GLOAD_LDS16((const char*)wtb + (size_t)(kk) * 8192 + tid * 16,         \
                    (char*)&Bs[buf][0] + wv * 1024);                           \
        const size_t r0_ = (size_t)((ia0 >= 0 && ia0 < n_vox) ? ia0 : n_vox);  \
        const size_t r1_ = (size_t)((ia1 >= 0 && ia1 < n_vox) ? ia1 : n_vox);  \
        const size_t r2_ = (size_t)((ia2 >= 0 && ia2 < n_vox) ? ia2 : n_vox);  \
        const size_t r3_ = (size_t)((ia3 >= 0 && ia3 < n_vox) ? ia3 : n_vox);  \
        char* ad_ = (char*)&As[buf][0] + wv * 4096;                            \
        GLOAD_LDS16((const char*)fb + r0_ * 128 + so, ad_);                    \
        GLOAD_LDS16((const char*)fb + r1_ * 128 + so, ad_ + 1024);             \
        GLOAD_LDS16((const char*)fb + r2_ * 128 + so, ad_ + 2048);             \
        GLOAD_LDS16((const char*)fb + r3_ * 128 + so, ad_ + 3072);             \
    } while (0)

    f32x4 acc[4][2];
    #pragma unroll
    for (int i = 0; i < 4; ++i)
        #pragma unroll
        for (int j = 0; j < 2; ++j)
            acc[i][j] = (f32x4){0.f, 0.f, 0.f, 0.f};

    LOADIDX(0);
    STAGE(0, 0);
    if (k3 > 1) LOADIDX(1);

    for (int k = 0; k < k3; ++k) {
        // implicit vmcnt(0)+lgkmcnt(0) drain: stage(k) complete, buf (k+1)&1
        // fully consumed by the previous iteration.
        __syncthreads();

        if (k + 1 < k3) STAGE((k + 1) & 1, k + 1);   // in flight across MFMA
        if (k + 2 < k3) LOADIDX(k + 2);

        const char* ab = (const char*)&As[k & 1][0];
        const char* bb = (const char*)&Bs[k & 1][0];
        #pragma unroll
        for (int ks = 0; ks < 2; ++ks) {
            const int kc = ks * 32 + l4 * 8;
            bf16x8 b0 = *(const bf16x8*)(bb + swz(wc + l15,      kc));
            bf16x8 b1 = *(const bf16x8*)(bb + swz(wc + 16 + l15, kc));
            #pragma unroll
            for (int mi = 0; mi < 4; ++mi) {
                bf16x8 a = *(const bf16x8*)(ab + swz(wr + mi * 16 + l15, kc));
                acc[mi][0] = __builtin_amdgcn_mfma_f32_16x16x32_bf16(a, b0, acc[mi][0], 0, 0, 0);
                acc[mi][1] = __builtin_amdgcn_mfma_f32_16x16x32_bf16(a, b1, acc[mi][1], 0, 0, 0);
            }
        }
    }

    // C/D layout: col = lane&15, row = (lane>>4)*4 + reg
    #pragma unroll
    for (int mi = 0; mi < 4; ++mi)
        #pragma unroll
        for (int ni = 0; ni < 2; ++ni)
            #pragma unroll
            for (int j = 0; j < 4; ++j) {
                const int row = n0 + wr + mi * 16 + l4 * 4 + j;
                const int col = wc + ni * 16 + l15;
                if (row < n_vox)
                    out[(size_t)row * D_OUT + col] = acc[mi][ni][j];
            }
    #undef LOADIDX
    #undef STAGE
}

// ---------------- fallback (round-1 kernel) --------------------------------
__global__ __launch_bounds__(512, 1) void subm_conv_mfma_v1(
    const float* __restrict__ feats,
    const int* __restrict__ indices,
    const float* __restrict__ weight,
    float* __restrict__ out,
    int n_vox, int k3)
{
    __shared__ bf16_t As[128 * 64];
    __shared__ bf16_t Bs[64 * 64];

    const int tid  = threadIdx.x;
    const int lane = tid & 63;
    const int wv   = tid >> 6;
    const int wr   = (wv >> 1) * 32;
    const int wc   = (wv & 1) * 32;
    const int l15  = lane & 15;
    const int l4   = lane >> 4;
    const int n0   = blockIdx.x * 128;

    const int ar = tid >> 2;
    const int ac = (tid & 3) * 16;
    const int bdp = tid & 63;
    const int bd0 = (tid >> 6) * 8;

    f32x4 acc[2][2];
    #pragma unroll
    for (int i = 0; i < 2; ++i)
        #pragma unroll
        for (int j = 0; j < 2; ++j)
            acc[i][j] = (f32x4){0.f, 0.f, 0.f, 0.f};

    for (int k = 0; k < k3; ++k) {
        __syncthreads();
        {
            const int n = n0 + ar;
            int idx = (n < n_vox) ? indices[(size_t)k * n_vox + n] : -1;
            bf16x8 v0 = {}, v1 = {};
            if (idx >= 0) {
                const float* src = feats + (size_t)idx * D_IN + ac;
                f32x4 f0 = *(const f32x4*)(src + 0);
                f32x4 f1 = *(const f32x4*)(src + 4);
                f32x4 f2 = *(const f32x4*)(src + 8);
                f32x4 f3 = *(const f32x4*)(src + 12);
                #pragma unroll
                for (int i = 0; i < 4; ++i) {
                    v0[i]     = (bf16_t)f0[i];
                    v0[i + 4] = (bf16_t)f1[i];
                    v1[i]     = (bf16_t)f2[i];
                    v1[i + 4] = (bf16_t)f3[i];
                }
            }
            *(bf16x8*)((char*)As + swz(ar, ac))     = v0;
            *(bf16x8*)((char*)As + swz(ar, ac + 8)) = v1;
        }
        {
            const float* wsrc = weight + (size_t)k * (D_IN * D_OUT) + (size_t)bd0 * D_OUT + bdp;
            bf16x8 v;
            #pragma unroll
            for (int i = 0; i < 8; ++i) v[i] = (bf16_t)wsrc[i * D_OUT];
            *(bf16x8*)((char*)Bs + swz(bdp, bd0)) = v;
        }
        __syncthreads();
        #pragma unroll
        for (int ks = 0; ks < 2; ++ks) {
            const int kc = ks * 32 + l4 * 8;
            bf16x8 a0 = *(const bf16x8*)((char*)As + swz(wr + l15,      kc));
            bf16x8 a1 = *(const bf16x8*)((char*)As + swz(wr + 16 + l15, kc));
            bf16x8 b0 = *(const bf16x8*)((char*)Bs + swz(wc + l15,      kc));
            bf16x8 b1 = *(const bf16x8*)((char*)Bs + swz(wc + 16 + l15, kc));
            acc[0][0] = __builtin_amdgcn_mfma_f32_16x16x32_bf16(a0, b0, acc[0][0], 0, 0, 0);
            acc[0][1] = __builtin_amdgcn_mfma_f32_16x16x32_bf16(a0, b1, acc[0][1], 0, 0, 0);
            acc[1][0] = __builtin_amdgcn_mfma_f32_16x16x32_bf16(a1, b0, acc[1][0], 0, 0, 0);
            acc[1][1] = __builtin_amdgcn_mfma_f32_16x16x32_bf16(a1, b1, acc[1][1], 0, 0, 0);
        }
    }

    #pragma unroll
    for (int mi = 0; mi < 2; ++mi)
        #pragma unroll
        for (int ni = 0; ni < 2; ++ni)
            #pragma unroll
            for (int j = 0; j < 4; ++j) {
                const int row = n0 + wr + mi * 16 + l4 * 4 + j;
                const int col = wc + ni * 16 + l15;
                if (row < n_vox)
                    out[(size_t)row * D_OUT + col] = acc[mi][ni][j];
            }
}

extern "C" void kernel_launch(void* const* d_in, const int* in_sizes, int n_in,
                              void* d_out, int out_size, void* d_ws, size_t ws_size,
                              hipStream_t stream) {
    const float* feats   = (const float*)d_in[0];
    const int*   indices = (const int*)d_in[1];
    const float* weight  = (const float*)d_in[2];
    float* out = (float*)d_out;

    const int n_vox = in_sizes[0] / D_IN;
    const int k3    = in_sizes[2] / (D_IN * D_OUT);

    const size_t fb_bytes  = (size_t)(n_vox + 1) * D_IN * sizeof(bf16_t);
    const size_t wt_off    = (fb_bytes + 255) & ~(size_t)255;
    const size_t wt_bytes  = (size_t)k3 * 64 * 64 * sizeof(bf16_t);
    const size_t need      = wt_off + wt_bytes;

    if (ws_size >= need && k3 >= 2) {
        bf16_t* fb  = (bf16_t*)((char*)d_ws);
        bf16_t* wtb = (bf16_t*)((char*)d_ws + wt_off);

        const int n_elems = n_vox * D_IN;
        const int total8  = (n_vox + 1) * (D_IN / 8);
        int cblocks = (total8 + 255) / 256;
        if (cblocks > 2048) cblocks = 2048;
        convert_feats<<<cblocks, 256, 0, stream>>>(feats, fb, n_elems, total8);
        convert_weight<<<k3, 512, 0, stream>>>(weight, wtb, k3);

        const int grid = (n_vox + BM - 1) / BM;
        subm_conv_256<<<grid, NTHREADS, 0, stream>>>(fb, indices, wtb, out, n_vox, k3);
    } else {
        const int grid = (n_vox + 127) / 128;
        subm_conv_mfma_v1<<<grid, 512, 0, stream>>>(feats, indices, weight, out, n_vox, k3);
    }
}

// Round 8
// 249.948 us; speedup vs baseline: 2.0211x; 1.0304x over previous
//
#include <hip/hip_runtime.h>
#include <hip/hip_bf16.h>
#include <stdint.h>

typedef __bf16 bf16_t;
typedef bf16_t bf16x8 __attribute__((ext_vector_type(8)));
typedef float f32x4 __attribute__((ext_vector_type(4)));

#define D_IN 64
#define D_OUT 64
#define BM 192
#define NTHREADS 512

#define GLOAD_LDS16(gsrc, ldst)                                                     \
    __builtin_amdgcn_global_load_lds(                                               \
        (const __attribute__((address_space(1))) uint32_t*)(gsrc),                  \
        (__attribute__((address_space(3))) uint32_t*)(ldst), 16, 0, 0)

// XOR-swizzled byte offset into a [rows][64] bf16 tile (row stride 128 B).
__device__ __forceinline__ uint32_t swz(int row, int col) {
    return (uint32_t)((row * 128 + col * 2) ^ ((row & 7) << 4));
}

// ---------------- pre-pass 1: feats fp32 -> bf16 (+ zero row at index N) ----
__global__ void convert_feats(const float* __restrict__ feats,
                              bf16_t* __restrict__ fb,
                              int n_elems, int total8) {
    int g = blockIdx.x * blockDim.x + threadIdx.x;
    for (; g < total8; g += gridDim.x * blockDim.x) {
        const int e = g * 8;
        bf16x8 v = {};
        if (e < n_elems) {
            f32x4 a = *(const f32x4*)(feats + e);
            f32x4 b = *(const f32x4*)(feats + e + 4);
            #pragma unroll
            for (int i = 0; i < 4; ++i) {
                v[i]     = (bf16_t)a[i];
                v[i + 4] = (bf16_t)b[i];
            }
        }
        *(bf16x8*)(fb + e) = v;
    }
}

// ---------------- pre-pass 2: weight -> plain transposed bf16 wt[k][dp][d] --
__global__ void convert_weight(const float* __restrict__ w,
                               bf16_t* __restrict__ wt, int k3) {
    const int k = blockIdx.x;
    const int tid = threadIdx.x;              // 512
    const int dp = tid >> 3;
    const int d0 = (tid & 7) * 8;
    const float* src = w + (size_t)k * (D_IN * D_OUT) + (size_t)d0 * D_OUT + dp;
    bf16x8 v;
    #pragma unroll
    for (int j = 0; j < 8; ++j) v[j] = (bf16_t)src[j * D_OUT];
    *(bf16x8*)((char*)wt + (size_t)k * 8192 + dp * 128 + d0 * 2) = v;
}

// ---------------- main kernel: BM=192, A-only LDS dbuf, B reg-staged ahead --
// 8 waves as 2(row)x4(col); each wave: 96 rows x 16 cols = acc[6].
// LDS = 48 KB -> 3 blocks/CU (24 waves). B(k+1) loaded into the alternate
// named register set during iter k (unroll-by-2); the barrier's vmcnt(0)
// drain guarantees validity with zero added stall.
__global__ __launch_bounds__(NTHREADS, 6) void subm_conv_192(
    const bf16_t* __restrict__ fb,      // (N+1) rows x 128 B, row N = zeros
    const int* __restrict__ indices,
    const bf16_t* __restrict__ wt,      // [k3][64][64] bf16, wt[k][dp][d]
    float* __restrict__ out,
    int n_vox, int k3)
{
    __shared__ __align__(16) bf16_t As[2][BM * 64];   // 2 x 24 KB = 48 KB

    const int tid  = threadIdx.x;
    const int lane = tid & 63;
    const int wv   = tid >> 6;
    const int l15  = lane & 15;
    const int l4   = lane >> 4;
    const int wr   = (wv & 1) * 96;     // wave row base: 0 or 96
    const int wc   = (wv >> 1) * 16;    // wave col base: 0,16,32,48
    const int n0   = blockIdx.x * BM;

    // A-staging: wave wv stages rows [wv*24, wv*24+24) = 3 issues of 8 rows.
    const int rbase = wv * 24 + (lane >> 3);
    const uint32_t so = (uint32_t)(((lane & 7) ^ ((lane >> 3) & 7)) * 16);

    int ia0, ia1, ia2;

    #define LOADIDX(kk) do {                                                   \
        const int* ip = indices + (size_t)(kk) * n_vox + n0 + rbase;           \
        ia0 = (n0 + rbase      < n_vox) ? ip[0]  : -1;                         \
        ia1 = (n0 + rbase + 8  < n_vox) ? ip[8]  : -1;                         \
        ia2 = (n0 + rbase + 16 < n_vox) ? ip[16] : -1;                         \
    } while (0)

    #define STAGE(buf, kk) do {                                                \
        const size_t r0_ = (size_t)((ia0 >= 0 && ia0 < n_vox) ? ia0 : n_vox);  \
        const size_t r1_ = (size_t)((ia1 >= 0 && ia1 < n_vox) ? ia1 : n_vox);  \
        const size_t r2_ = (size_t)((ia2 >= 0 && ia2 < n_vox) ? ia2 : n_vox);  \
        char* ad_ = (char*)&As[buf][0] + wv * 3072;                            \
        GLOAD_LDS16((const char*)fb + r0_ * 128 + so, ad_);                    \
        GLOAD_LDS16((const char*)fb + r1_ * 128 + so, ad_ + 1024);             \
        GLOAD_LDS16((const char*)fb + r2_ * 128 + so, ad_ + 2048);             \
    } while (0)

    // B register fragments: wave's 16 cols x 64 d. b0 = ks0, b1 = ks1.
    #define LOADB(b0_, b1_, kk) do {                                           \
        const char* wb_ = (const char*)wt + (size_t)(kk) * 8192                \
                        + (size_t)(wc + l15) * 128 + l4 * 16;                  \
        b0_ = *(const bf16x8*)(wb_);                                           \
        b1_ = *(const bf16x8*)(wb_ + 64);                                      \
    } while (0)

    #define MFMA_BODY(buf, b0_, b1_) do {                                      \
        const char* ab_ = (const char*)&As[buf][0];                            \
        _Pragma("unroll")                                                      \
        for (int mi = 0; mi < 6; ++mi) {                                       \
            bf16x8 a0_ = *(const bf16x8*)(ab_ + swz(wr + mi * 16 + l15, l4 * 8));       \
            acc[mi] = __builtin_amdgcn_mfma_f32_16x16x32_bf16(a0_, b0_, acc[mi], 0, 0, 0); \
        }                                                                      \
        _Pragma("unroll")                                                      \
        for (int mi = 0; mi < 6; ++mi) {                                       \
            bf16x8 a1_ = *(const bf16x8*)(ab_ + swz(wr + mi * 16 + l15, 32 + l4 * 8));  \
            acc[mi] = __builtin_amdgcn_mfma_f32_16x16x32_bf16(a1_, b1_, acc[mi], 0, 0, 0); \
        }                                                                      \
    } while (0)

    f32x4 acc[6];
    #pragma unroll
    for (int i = 0; i < 6; ++i)
        acc[i] = (f32x4){0.f, 0.f, 0.f, 0.f};

    bf16x8 bE0, bE1, bO0, bO1;

    LOADIDX(0);
    STAGE(0, 0);
    LOADB(bE0, bE1, 0);
    if (k3 > 1) LOADIDX(1);

    int k = 0;
    while (true) {
        // even phase: compute k from buf 0 / bE
        __syncthreads();                      // drains vmcnt(0): stage(k), B(k) done
        if (k + 1 < k3) { STAGE(1, k + 1); LOADB(bO0, bO1, k + 1); }
        if (k + 2 < k3) LOADIDX(k + 2);
        MFMA_BODY(0, bE0, bE1);
        ++k; if (k >= k3) break;

        // odd phase: compute k from buf 1 / bO
        __syncthreads();
        if (k + 1 < k3) { STAGE(0, k + 1); LOADB(bE0, bE1, k + 1); }
        if (k + 2 < k3) LOADIDX(k + 2);
        MFMA_BODY(1, bO0, bO1);
        ++k; if (k >= k3) break;
    }

    // C/D layout: col = lane&15, row = (lane>>4)*4 + reg
    #pragma unroll
    for (int mi = 0; mi < 6; ++mi)
        #pragma unroll
        for (int j = 0; j < 4; ++j) {
            const int row = n0 + wr + mi * 16 + l4 * 4 + j;
            const int col = wc + l15;
            if (row < n_vox)
                out[(size_t)row * D_OUT + col] = acc[mi][j];
        }
    #undef LOADIDX
    #undef STAGE
    #undef LOADB
    #undef MFMA_BODY
}

// ---------------- fallback (round-1 kernel) --------------------------------
__global__ __launch_bounds__(512, 1) void subm_conv_mfma_v1(
    const float* __restrict__ feats,
    const int* __restrict__ indices,
    const float* __restrict__ weight,
    float* __restrict__ out,
    int n_vox, int k3)
{
    __shared__ bf16_t As[128 * 64];
    __shared__ bf16_t Bs[64 * 64];

    const int tid  = threadIdx.x;
    const int lane = tid & 63;
    const int wv   = tid >> 6;
    const int wr   = (wv >> 1) * 32;
    const int wc   = (wv & 1) * 32;
    const int l15  = lane & 15;
    const int l4   = lane >> 4;
    const int n0   = blockIdx.x * 128;

    const int ar = tid >> 2;
    const int ac = (tid & 3) * 16;
    const int bdp = tid & 63;
    const int bd0 = (tid >> 6) * 8;

    f32x4 acc[2][2];
    #pragma unroll
    for (int i = 0; i < 2; ++i)
        #pragma unroll
        for (int j = 0; j < 2; ++j)
            acc[i][j] = (f32x4){0.f, 0.f, 0.f, 0.f};

    for (int k = 0; k < k3; ++k) {
        __syncthreads();
        {
            const int n = n0 + ar;
            int idx = (n < n_vox) ? indices[(size_t)k * n_vox + n] : -1;
            bf16x8 v0 = {}, v1 = {};
            if (idx >= 0) {
                const float* src = feats + (size_t)idx * D_IN + ac;
                f32x4 f0 = *(const f32x4*)(src + 0);
                f32x4 f1 = *(const f32x4*)(src + 4);
                f32x4 f2 = *(const f32x4*)(src + 8);
                f32x4 f3 = *(const f32x4*)(src + 12);
                #pragma unroll
                for (int i = 0; i < 4; ++i) {
                    v0[i]     = (bf16_t)f0[i];
                    v0[i + 4] = (bf16_t)f1[i];
                    v1[i]     = (bf16_t)f2[i];
                    v1[i + 4] = (bf16_t)f3[i];
                }
            }
            auto swz = [](int row, int col) -> uint32_t {
                return (uint32_t)((row * 128 + col * 2) ^ ((row & 7) << 4));
            };
            *(bf16x8*)((char*)As + swz(ar, ac))     = v0;
            *(bf16x8*)((char*)As + swz(ar, ac + 8)) = v1;
        }
        {
            const float* wsrc = weight + (size_t)k * (D_IN * D_OUT) + (size_t)bd0 * D_OUT + bdp;
            bf16x8 v;
            #pragma unroll
            for (int i = 0; i < 8; ++i) v[i] = (bf16_t)wsrc[i * D_OUT];
            auto swz = [](int row, int col) -> uint32_t {
                return (uint32_t)((row * 128 + col * 2) ^ ((row & 7) << 4));
            };
            *(bf16x8*)((char*)Bs + swz(bdp, bd0)) = v;
        }
        __syncthreads();
        #pragma unroll
        for (int ks = 0; ks < 2; ++ks) {
            const int kc = ks * 32 + l4 * 8;
            bf16x8 a0 = *(const bf16x8*)((char*)As + swz(wr + l15,      kc));
            bf16x8 a1 = *(const bf16x8*)((char*)As + swz(wr + 16 + l15, kc));
            bf16x8 b0 = *(const bf16x8*)((char*)Bs + swz(wc + l15,      kc));
            bf16x8 b1 = *(const bf16x8*)((char*)Bs + swz(wc + 16 + l15, kc));
            acc[0][0] = __builtin_amdgcn_mfma_f32_16x16x32_bf16(a0, b0, acc[0][0], 0, 0, 0);
            acc[0][1] = __builtin_amdgcn_mfma_f32_16x16x32_bf16(a0, b1, acc[0][1], 0, 0, 0);
            acc[1][0] = __builtin_amdgcn_mfma_f32_16x16x32_bf16(a1, b0, acc[1][0], 0, 0, 0);
            acc[1][1] = __builtin_amdgcn_mfma_f32_16x16x32_bf16(a1, b1, acc[1][1], 0, 0, 0);
        }
    }

    #pragma unroll
    for (int mi = 0; mi < 2; ++mi)
        #pragma unroll
        for (int ni = 0; ni < 2; ++ni)
            #pragma unroll
            for (int j = 0; j < 4; ++j) {
                const int row = n0 + wr + mi * 16 + l4 * 4 + j;
                const int col = wc + ni * 16 + l15;
                if (row < n_vox)
                    out[(size_t)row * D_OUT + col] = acc[mi][ni][j];
            }
}

extern "C" void kernel_launch(void* const* d_in, const int* in_sizes, int n_in,
                              void* d_out, int out_size, void* d_ws, size_t ws_size,
                              hipStream_t stream) {
    const float* feats   = (const float*)d_in[0];
    const int*   indices = (const int*)d_in[1];
    const float* weight  = (const float*)d_in[2];
    float* out = (float*)d_out;

    const int n_vox = in_sizes[0] / D_IN;
    const int k3    = in_sizes[2] / (D_IN * D_OUT);

    const size_t fb_bytes  = (size_t)(n_vox + 1) * D_IN * sizeof(bf16_t);
    const size_t wt_off    = (fb_bytes + 255) & ~(size_t)255;
    const size_t wt_bytes  = (size_t)k3 * 64 * 64 * sizeof(bf16_t);
    const size_t need      = wt_off + wt_bytes;

    if (ws_size >= need && k3 >= 2) {
        bf16_t* fb = (bf16_t*)((char*)d_ws);
        bf16_t* wt = (bf16_t*)((char*)d_ws + wt_off);

        const int n_elems = n_vox * D_IN;
        const int total8  = (n_vox + 1) * (D_IN / 8);
        int cblocks = (total8 + 255) / 256;
        if (cblocks > 2048) cblocks = 2048;
        convert_feats<<<cblocks, 256, 0, stream>>>(feats, fb, n_elems, total8);
        convert_weight<<<k3, 512, 0, stream>>>(weight, wt, k3);

        const int grid = (n_vox + BM - 1) / BM;
        subm_conv_192<<<grid, NTHREADS, 0, stream>>>(fb, indices, wt, out, n_vox, k3);
    } else {
        const int grid = (n_vox + 127) / 128;
        subm_conv_mfma_v1<<<grid, 512, 0, stream>>>(feats, indices, weight, out, n_vox, k3);
    }
}